// Round 2
// baseline (377.885 us; speedup 1.0000x reference)
//
#include <hip/hip_runtime.h>

using u16 = unsigned short;
typedef __attribute__((ext_vector_type(8))) short bf16x8;
typedef __attribute__((ext_vector_type(4))) float f32x4;
typedef __attribute__((ext_vector_type(4))) unsigned short u16x4;

#define MFMA16(a,b,c) __builtin_amdgcn_mfma_f32_16x16x32_bf16((a),(b),(c),0,0,0)

__device__ __forceinline__ u16 f2bf(float f){
  unsigned int x = __builtin_bit_cast(unsigned int, f);
  x += 0x7fffu + ((x >> 16) & 1u);
  return (u16)(x >> 16);
}
__device__ __forceinline__ float bf2f(u16 u){
  unsigned int x = ((unsigned int)u) << 16;
  return __builtin_bit_cast(float, x);
}

__global__ __launch_bounds__(256) void cvt_kernel(const float* __restrict__ in, u16* __restrict__ out, int n4){
  int i = blockIdx.x*256 + threadIdx.x;
  if (i >= n4) return;
  float4 v = reinterpret_cast<const float4*>(in)[i];
  u16x4 o = { f2bf(v.x), f2bf(v.y), f2bf(v.z), f2bf(v.w) };
  reinterpret_cast<u16x4*>(out)[i] = o;
}

// pe table [2176][512], rows >= 2048 are zero padding. f64 trig: f32 pow/sin at
// theta ~ 2000 rad would give ~0.02 abs angle error.
__global__ __launch_bounds__(256) void pe_fill(u16* __restrict__ pe){
  int d = blockIdx.x, m = threadIdx.x;
  float s = 0.f, c = 0.f;
  if (d < 2048){
    double freq = pow(10000.0, -(double)m * (1.0/256.0));
    double th = (double)d * freq;
    s = (float)sin(th);
    c = (float)cos(th);
  }
  size_t o = (size_t)d*512 + 2*m;
  pe[o]   = f2bf(s);
  pe[o+1] = f2bf(c);
}

__global__ __launch_bounds__(256) void bias_combine(const float* __restrict__ bq, const float* __restrict__ bu,
                                                    const float* __restrict__ bvv,
                                                    float* __restrict__ ou, float* __restrict__ ov){
  int n = blockIdx.x*256 + threadIdx.x;
  if (n < 512){ ou[n] = bq[n] + bu[n]; ov[n] = bq[n] + bvv[n]; }
}

// C[M,512] = A[M,512] @ B[512,512]^T (+bias). A,B bf16 row-major, K-contiguous.
// modes: 0 QUQV (dual out, [b][h][t][dk]), 1 KH ([b][h][t][dk]), 2 VT ([b][h][dk][t]),
//        3 RPH ([h][2176][dk], no bias), 4 OUT (f32 row-major)
template<int MODE>
__global__ __launch_bounds__(256) void gemm_k(
    const u16* __restrict__ A, const u16* __restrict__ Bm,
    const float* __restrict__ bias, const float* __restrict__ bias2,
    void* __restrict__ o1, void* __restrict__ o2)
{
  const int tid = threadIdx.x;
  const int wid = tid >> 6, l = tid & 63, lr = l & 15, lg = l >> 4;
  const int wm = wid >> 1, wn = wid & 1;
  const int row0 = blockIdx.y * 128, col0 = blockIdx.x * 128;
  __shared__ u16 As[128][40];   // BK=32, +8 pad -> 80B row stride, 2-way-free banks
  __shared__ u16 Bs[128][40];
  f32x4 acc[4][4];
  #pragma unroll
  for (int a=0;a<4;a++)
    #pragma unroll
    for (int b=0;b<4;b++) acc[a][b] = (f32x4){0.f,0.f,0.f,0.f};
  const int sr = tid >> 1, sc = (tid & 1) * 16;
  const u16* Ag = A  + (size_t)(row0 + sr) * 512 + sc;
  const u16* Bg = Bm + (size_t)(col0 + sr) * 512 + sc;
  for (int k0 = 0; k0 < 512; k0 += 32){
    float4 a0 = *reinterpret_cast<const float4*>(Ag + k0);
    float4 a1 = *reinterpret_cast<const float4*>(Ag + k0 + 8);
    float4 b0 = *reinterpret_cast<const float4*>(Bg + k0);
    float4 b1 = *reinterpret_cast<const float4*>(Bg + k0 + 8);
    __syncthreads();
    *reinterpret_cast<float4*>(&As[sr][sc])   = a0;
    *reinterpret_cast<float4*>(&As[sr][sc+8]) = a1;
    *reinterpret_cast<float4*>(&Bs[sr][sc])   = b0;
    *reinterpret_cast<float4*>(&Bs[sr][sc+8]) = b1;
    __syncthreads();
    bf16x8 af[4], bfr[4];
    #pragma unroll
    for (int mi=0;mi<4;mi++) af[mi]  = *reinterpret_cast<const bf16x8*>(&As[wm*64 + mi*16 + lr][lg*8]);
    #pragma unroll
    for (int ni=0;ni<4;ni++) bfr[ni] = *reinterpret_cast<const bf16x8*>(&Bs[wn*64 + ni*16 + lr][lg*8]);
    #pragma unroll
    for (int mi=0;mi<4;mi++)
      #pragma unroll
      for (int ni=0;ni<4;ni++)
        acc[mi][ni] = MFMA16(af[mi], bfr[ni], acc[mi][ni]);
  }
  #pragma unroll
  for (int mi=0;mi<4;mi++){
    #pragma unroll
    for (int ni=0;ni<4;ni++){
      #pragma unroll
      for (int t=0;t<4;t++){
        const int r = row0 + wm*64 + mi*16 + lg*4 + t;  // C/D: row=(lg)*4+t, col=lr
        const int c = col0 + wn*64 + ni*16 + lr;
        float v = acc[mi][ni][t];
        if (MODE == 0){
          const int b_ = r >> 11, t_ = r & 2047, h = c >> 6, dk = c & 63;
          const size_t o = ((size_t)(b_*8 + h)*2048 + t_)*64 + dk;
          ((u16*)o1)[o] = f2bf(v + bias[c]);
          ((u16*)o2)[o] = f2bf(v + bias2[c]);
        } else if (MODE == 1){
          const int b_ = r >> 11, t_ = r & 2047, h = c >> 6, dk = c & 63;
          const size_t o = ((size_t)(b_*8 + h)*2048 + t_)*64 + dk;
          ((u16*)o1)[o] = f2bf(v + bias[c]);
        } else if (MODE == 2){
          const int b_ = r >> 11, t_ = r & 2047, h = c >> 6, dk = c & 63;
          const size_t o = ((size_t)(b_*8 + h)*64 + dk)*2048 + t_;
          ((u16*)o1)[o] = f2bf(v + bias[c]);
        } else if (MODE == 3){
          const int h = c >> 6, dk = c & 63;
          const size_t o = ((size_t)h*2176 + r)*64 + dk;
          ((u16*)o1)[o] = f2bf(v);
        } else {
          ((float*)o1)[(size_t)r*512 + c] = v + bias[c];
        }
      }
    }
  }
}

// Flash attention with rel-pos bd band.
// grid (32 q-tiles, 32 b*h), 256 thr = 4 waves, each wave owns 16 q rows.
__global__ __launch_bounds__(256) void attn_k(
  const u16* __restrict__ qu, const u16* __restrict__ qv,
  const u16* __restrict__ kh, const u16* __restrict__ vt,
  const u16* __restrict__ rph, u16* __restrict__ aout)
{
  const int tid = threadIdx.x, wid = tid >> 6, l = tid & 63, lr = l & 15, lg = l >> 4;
  const int bh = blockIdx.y, b = bh >> 3, h = bh & 7;
  const int i0 = blockIdx.x * 64;
  __shared__ u16 Ks[64][72];       // [j][dk]
  __shared__ u16 Vs[64][72];       // [dk][j]
  __shared__ u16 Rs[128][72];      // [d-dstart][dk]
  __shared__ u16 Ds[4][16][136];   // per-wave bd band, bf16
  __shared__ u16 Ps[4][16][72];    // per-wave probs
  const u16* quB = qu + ((size_t)bh*2048 + i0 + wid*16 + lr)*64;
  const u16* qvB = qv + ((size_t)bh*2048 + i0 + wid*16 + lr)*64;
  bf16x8 qa[2], qva[2];
  qa[0]  = *reinterpret_cast<const bf16x8*>(quB + lg*8);
  qa[1]  = *reinterpret_cast<const bf16x8*>(quB + 32 + lg*8);
  qva[0] = *reinterpret_cast<const bf16x8*>(qvB + lg*8);
  qva[1] = *reinterpret_cast<const bf16x8*>(qvB + 32 + lg*8);
  float m_run[4], l_run[4];
  f32x4 acc_o[4];
  #pragma unroll
  for (int t=0;t<4;t++){ m_run[t] = -3.0e38f; l_run[t] = 0.f; }
  #pragma unroll
  for (int dt=0;dt<4;dt++) acc_o[dt] = (f32x4){0.f,0.f,0.f,0.f};
  const int srow = tid >> 3, scol8 = (tid & 7)*8;
  for (int j0 = 0; j0 < 2048; j0 += 64){
    const bool bda = (j0 <= i0);
    int ds_ = i0 - j0 - 63; if (ds_ < 0) ds_ = 0;
    const int dstart = ds_;
    #pragma unroll
    for (int p=0;p<2;p++){
      const int r = p*32 + srow;
      *reinterpret_cast<float4*>(&Ks[r][scol8]) =
        *reinterpret_cast<const float4*>(kh + ((size_t)bh*2048 + j0 + r)*64 + scol8);
      *reinterpret_cast<float4*>(&Vs[r][scol8]) =
        *reinterpret_cast<const float4*>(vt + ((size_t)bh*64 + r)*2048 + j0 + scol8);
    }
    if (bda){
      #pragma unroll
      for (int p=0;p<4;p++){
        const int r = p*32 + srow;
        *reinterpret_cast<float4*>(&Rs[r][scol8]) =
          *reinterpret_cast<const float4*>(rph + ((size_t)h*2176 + dstart + r)*64 + scol8);
      }
    }
    __syncthreads();
    // QK^T
    f32x4 sc4[4];
    #pragma unroll
    for (int jt=0;jt<4;jt++){
      f32x4 a = (f32x4){0.f,0.f,0.f,0.f};
      #pragma unroll
      for (int ks=0;ks<2;ks++){
        bf16x8 kb = *reinterpret_cast<const bf16x8*>(&Ks[jt*16+lr][ks*32+lg*8]);
        a = MFMA16(qa[ks], kb, a);
      }
      sc4[jt] = a;
    }
    // bd band: Dt[16 q][128 d] = Qv @ Rph^T
    if (bda){
      #pragma unroll
      for (int dt=0;dt<8;dt++){
        f32x4 a = (f32x4){0.f,0.f,0.f,0.f};
        #pragma unroll
        for (int ks=0;ks<2;ks++){
          bf16x8 rb = *reinterpret_cast<const bf16x8*>(&Rs[dt*16+lr][ks*32+lg*8]);
          a = MFMA16(qva[ks], rb, a);
        }
        #pragma unroll
        for (int t=0;t<4;t++) Ds[wid][lg*4+t][dt*16+lr] = f2bf(a[t]);
      }
    }
    __syncthreads();
    // online softmax (rows owned by lane: r = lg*4+t, cols lr across 16 lanes)
    #pragma unroll
    for (int t=0;t<4;t++){
      const int iloc = lg*4 + t;
      const int ig = i0 + wid*16 + iloc;
      float sv[4];
      float sm = -3.0e38f;
      #pragma unroll
      for (int jt=0;jt<4;jt++){
        float s = sc4[jt][t];
        const int jg = j0 + jt*16 + lr;
        if (bda && jg <= ig) s += bf2f(Ds[wid][iloc][ig - jg - dstart]);
        s *= 0.125f;
        sv[jt] = s;
        sm = fmaxf(sm, s);
      }
      #pragma unroll
      for (int mm=1;mm<16;mm<<=1) sm = fmaxf(sm, __shfl_xor(sm, mm, 64));
      const float mn = fmaxf(m_run[t], sm);
      const float scl = __expf(m_run[t] - mn);
      float pp = 0.f;
      #pragma unroll
      for (int jt=0;jt<4;jt++){
        float p = __expf(sv[jt] - mn);
        pp += p;
        Ps[wid][iloc][jt*16+lr] = f2bf(p);
      }
      #pragma unroll
      for (int mm=1;mm<16;mm<<=1) pp += __shfl_xor(pp, mm, 64);
      l_run[t] = l_run[t]*scl + pp;
      m_run[t] = mn;
      // rescale ONLY this row's accumulator element (element t of each f32x4)
      #pragma unroll
      for (int dt=0;dt<4;dt++) acc_o[dt][t] *= scl;
    }
    __syncthreads();
    // PV
    bf16x8 pa[2];
    pa[0] = *reinterpret_cast<const bf16x8*>(&Ps[wid][lr][lg*8]);
    pa[1] = *reinterpret_cast<const bf16x8*>(&Ps[wid][lr][32+lg*8]);
    #pragma unroll
    for (int dt=0;dt<4;dt++){
      #pragma unroll
      for (int ks=0;ks<2;ks++){
        bf16x8 vb = *reinterpret_cast<const bf16x8*>(&Vs[dt*16+lr][ks*32+lg*8]);
        acc_o[dt] = MFMA16(pa[ks], vb, acc_o[dt]);
      }
    }
    __syncthreads();
  }
  #pragma unroll
  for (int dt=0;dt<4;dt++){
    #pragma unroll
    for (int t=0;t<4;t++){
      const int ig = i0 + wid*16 + lg*4 + t;
      const int dk = dt*16 + lr;
      const float v = acc_o[dt][t] / l_run[t];
      aout[((size_t)b*2048 + ig)*512 + h*64 + dk] = f2bf(v);
    }
  }
}

extern "C" void kernel_launch(void* const* d_in, const int* in_sizes, int n_in,
                              void* d_out, int out_size, void* d_ws, size_t ws_size,
                              hipStream_t stream)
{
  const float* q  = (const float*)d_in[0];
  const float* k  = (const float*)d_in[1];
  const float* v  = (const float*)d_in[2];
  // d_in[3] = mask: all-true in this problem, ignored
  const float* Wq = (const float*)d_in[4];
  const float* bq = (const float*)d_in[5];
  const float* Wk = (const float*)d_in[6];
  const float* bk = (const float*)d_in[7];
  const float* Wv = (const float*)d_in[8];
  const float* bv = (const float*)d_in[9];
  const float* Wp = (const float*)d_in[10];
  const float* bu = (const float*)d_in[11];
  const float* bvv= (const float*)d_in[12];
  const float* Wo = (const float*)d_in[13];
  const float* bo = (const float*)d_in[14];
  (void)in_sizes; (void)n_in; (void)out_size; (void)ws_size;

  char* ws = (char*)d_ws;
  size_t off = 0;
  auto alloc = [&](size_t bytes) -> void* {
    void* p = ws + off;
    off += (bytes + 255) & ~((size_t)255);
    return p;
  };
  u16* qbf = (u16*)alloc((size_t)8192*512*2);
  u16* kbf = (u16*)alloc((size_t)8192*512*2);
  u16* vbf = (u16*)alloc((size_t)8192*512*2);
  u16* Wqb = (u16*)alloc((size_t)512*512*2);
  u16* Wkb = (u16*)alloc((size_t)512*512*2);
  u16* Wvb = (u16*)alloc((size_t)512*512*2);
  u16* Wpb = (u16*)alloc((size_t)512*512*2);
  u16* Wob = (u16*)alloc((size_t)512*512*2);
  u16* pe  = (u16*)alloc((size_t)2176*512*2);
  float* bias_qu = (float*)alloc(512*4);
  float* bias_qv = (float*)alloc(512*4);
  u16* quB  = (u16*)alloc((size_t)4194304*2);
  u16* qvB  = (u16*)alloc((size_t)4194304*2);
  u16* khB  = (u16*)alloc((size_t)4194304*2);
  u16* vtB  = (u16*)alloc((size_t)4194304*2);
  u16* rphB = (u16*)alloc((size_t)8*2176*64*2);
  u16* aoutB= (u16*)alloc((size_t)4194304*2);

  cvt_kernel<<<4096,256,0,stream>>>(q, qbf, 1048576);
  cvt_kernel<<<4096,256,0,stream>>>(k, kbf, 1048576);
  cvt_kernel<<<4096,256,0,stream>>>(v, vbf, 1048576);
  cvt_kernel<<<256,256,0,stream>>>(Wq, Wqb, 65536);
  cvt_kernel<<<256,256,0,stream>>>(Wk, Wkb, 65536);
  cvt_kernel<<<256,256,0,stream>>>(Wv, Wvb, 65536);
  cvt_kernel<<<256,256,0,stream>>>(Wp, Wpb, 65536);
  cvt_kernel<<<256,256,0,stream>>>(Wo, Wob, 65536);
  bias_combine<<<2,256,0,stream>>>(bq, bu, bvv, bias_qu, bias_qv);
  pe_fill<<<2176,256,0,stream>>>(pe);

  gemm_k<0><<<dim3(4,64),256,0,stream>>>(qbf, Wqb, bias_qu, bias_qv, quB, qvB);
  gemm_k<1><<<dim3(4,64),256,0,stream>>>(kbf, Wkb, bk, nullptr, khB, nullptr);
  gemm_k<2><<<dim3(4,64),256,0,stream>>>(vbf, Wvb, bv, nullptr, vtB, nullptr);
  gemm_k<3><<<dim3(4,17),256,0,stream>>>(pe, Wpb, nullptr, nullptr, rphB, nullptr);

  attn_k<<<dim3(32,32),256,0,stream>>>(quB, qvB, khB, vtB, rphB, aoutB);

  gemm_k<4><<<dim3(4,64),256,0,stream>>>(aoutB, Wob, bo, nullptr, d_out, nullptr);
}